// Round 1
// baseline (517.293 us; speedup 1.0000x reference)
//
#include <hip/hip_runtime.h>

typedef _Float16 half8 __attribute__((ext_vector_type(8)));
typedef _Float16 half4v __attribute__((ext_vector_type(4)));
typedef float float4v __attribute__((ext_vector_type(4)));

#define BN 2048
#define BD 512
#define NK 32        // keys per tile
#define LDK 520      // K_lds pitch (fp16 elems): 1040 B, 16B-aligned rows, bank stride 4
#define LDV 36       // Vt pitch (fp16 elems): 72 B, 8B-aligned, odd-ish bank spread
#define LDP 40       // P pitch  (fp16 elems): 80 B, 16B-aligned
#define L2E 1.44269504f

__global__ __launch_bounds__(256, 2)
void attn_kernel(const float* __restrict__ x, float* __restrict__ y)
{
    __shared__ __align__(16) _Float16 Kl[NK * LDK];    // 33,280 B  row-major [key][dim]
    __shared__ __align__(16) _Float16 Vt[BD * LDV];    // 36,864 B  transposed [dim][key]
    __shared__ __align__(16) _Float16 Pl[4 * 16 * LDP];//  5,120 B  per-wave P buffer

    const int t      = threadIdx.x;
    const int w      = t >> 6;        // wave id 0..3
    const int lane   = t & 63;
    const int lane15 = lane & 15;
    const int quad   = lane >> 4;

    const int b  = blockIdx.y;
    const int q0 = blockIdx.x * 64;

    const float* xb = x + ((size_t)b * BN * BD);

    // ---- preload this wave's 16 Q rows as A-fragments (A[m=lane15][k=quad*8+j]) ----
    half8 qf[16];
    {
        const float* qrow = xb + (size_t)(q0 + w * 16 + lane15) * BD + quad * 8;
        #pragma unroll
        for (int ks = 0; ks < 16; ++ks) {
            float4v a = *(const float4v*)(qrow + ks * 32);
            float4v c = *(const float4v*)(qrow + ks * 32 + 4);
            half8 q;
            q[0] = (_Float16)a[0]; q[1] = (_Float16)a[1];
            q[2] = (_Float16)a[2]; q[3] = (_Float16)a[3];
            q[4] = (_Float16)c[0]; q[5] = (_Float16)c[1];
            q[6] = (_Float16)c[2]; q[7] = (_Float16)c[3];
            qf[ks] = q;
        }
    }

    const int d4 = t & 15;   // staging: dim-quad lane
    const int kp = t >> 4;   // staging: key-pair 0..15

    float m_r[4], l_r[4];
    #pragma unroll
    for (int r = 0; r < 4; ++r) { m_r[r] = -1e30f; l_r[r] = 0.0f; }

    // ================= phase 1: exact row max & softmax denom =================
    for (int kt = 0; kt < BN / NK; ++kt) {
        __syncthreads();
        {   // stage K tile (row-major only)
            const float* r0 = xb + (size_t)(kt * NK + 2 * kp) * BD;
            const float* r1 = r0 + BD;
            #pragma unroll
            for (int it = 0; it < 8; ++it) {
                const int d = (d4 + (it << 4)) << 2;   // 4*(d4+16*it)
                float4v fa = *(const float4v*)(r0 + d);
                float4v fb = *(const float4v*)(r1 + d);
                half4v ha, hb;
                ha[0] = (_Float16)fa[0]; ha[1] = (_Float16)fa[1];
                ha[2] = (_Float16)fa[2]; ha[3] = (_Float16)fa[3];
                hb[0] = (_Float16)fb[0]; hb[1] = (_Float16)fb[1];
                hb[2] = (_Float16)fb[2]; hb[3] = (_Float16)fb[3];
                *(half4v*)(&Kl[(2 * kp)     * LDK + d]) = ha;
                *(half4v*)(&Kl[(2 * kp + 1) * LDK + d]) = hb;
            }
        }
        __syncthreads();

        float4v s0 = {0.f, 0.f, 0.f, 0.f}, s1 = {0.f, 0.f, 0.f, 0.f};
        {
            const _Float16* kr0 = &Kl[lane15 * LDK + quad * 8];
            const _Float16* kr1 = &Kl[(16 + lane15) * LDK + quad * 8];
            #pragma unroll
            for (int ks = 0; ks < 16; ++ks) {
                half8 b0 = *(const half8*)(kr0 + ks * 32);
                half8 b1 = *(const half8*)(kr1 + ks * 32);
                s0 = __builtin_amdgcn_mfma_f32_16x16x32_f16(qf[ks], b0, s0, 0, 0, 0);
                s1 = __builtin_amdgcn_mfma_f32_16x16x32_f16(qf[ks], b1, s1, 0, 0, 0);
            }
        }
        // online stats: rows quad*4+r, cols = lane15 (+16)
        #pragma unroll
        for (int r = 0; r < 4; ++r) {
            float mx = fmaxf(s0[r], s1[r]);
            mx = fmaxf(mx, __shfl_xor(mx, 1));
            mx = fmaxf(mx, __shfl_xor(mx, 2));
            mx = fmaxf(mx, __shfl_xor(mx, 4));
            mx = fmaxf(mx, __shfl_xor(mx, 8));
            float mn = fmaxf(m_r[r], mx);
            float es = exp2f((s0[r] - mn) * L2E) + exp2f((s1[r] - mn) * L2E);
            es += __shfl_xor(es, 1);
            es += __shfl_xor(es, 2);
            es += __shfl_xor(es, 4);
            es += __shfl_xor(es, 8);
            l_r[r] = l_r[r] * exp2f((m_r[r] - mn) * L2E) + es;
            m_r[r] = mn;
        }
    }

    float linv[4];
    #pragma unroll
    for (int r = 0; r < 4; ++r) linv[r] = 1.0f / l_r[r];

    float4v accO[32];
    #pragma unroll
    for (int nt = 0; nt < 32; ++nt) accO[nt] = (float4v){0.f, 0.f, 0.f, 0.f};

    // ================= phase 2: P = softmax(S), O += P*V =================
    for (int kt = 0; kt < BN / NK; ++kt) {
        __syncthreads();
        {   // stage K tile row-major + V tile transposed
            const float* r0 = xb + (size_t)(kt * NK + 2 * kp) * BD;
            const float* r1 = r0 + BD;
            #pragma unroll
            for (int it = 0; it < 8; ++it) {
                const int d = (d4 + (it << 4)) << 2;
                float4v fa = *(const float4v*)(r0 + d);
                float4v fb = *(const float4v*)(r1 + d);
                half4v ha, hb;
                ha[0] = (_Float16)fa[0]; ha[1] = (_Float16)fa[1];
                ha[2] = (_Float16)fa[2]; ha[3] = (_Float16)fa[3];
                hb[0] = (_Float16)fb[0]; hb[1] = (_Float16)fb[1];
                hb[2] = (_Float16)fb[2]; hb[3] = (_Float16)fb[3];
                *(half4v*)(&Kl[(2 * kp)     * LDK + d]) = ha;
                *(half4v*)(&Kl[(2 * kp + 1) * LDK + d]) = hb;
                #pragma unroll
                for (int i = 0; i < 4; ++i) {
                    // Vt[dim][key]: pack the two key-neighbors into one dword write
                    typedef _Float16 half2v __attribute__((ext_vector_type(2)));
                    half2v p; p[0] = ha[i]; p[1] = hb[i];
                    *(half2v*)(&Vt[(d + i) * LDV + 2 * kp]) = p;
                }
            }
        }
        __syncthreads();

        float4v s0 = {0.f, 0.f, 0.f, 0.f}, s1 = {0.f, 0.f, 0.f, 0.f};
        {
            const _Float16* kr0 = &Kl[lane15 * LDK + quad * 8];
            const _Float16* kr1 = &Kl[(16 + lane15) * LDK + quad * 8];
            #pragma unroll
            for (int ks = 0; ks < 16; ++ks) {
                half8 b0 = *(const half8*)(kr0 + ks * 32);
                half8 b1 = *(const half8*)(kr1 + ks * 32);
                s0 = __builtin_amdgcn_mfma_f32_16x16x32_f16(qf[ks], b0, s0, 0, 0, 0);
                s1 = __builtin_amdgcn_mfma_f32_16x16x32_f16(qf[ks], b1, s1, 0, 0, 0);
            }
        }

        // P = exp(s - m)/l in fp16, staged per-wave in LDS (C/D layout -> A layout)
        _Float16* Pw = &Pl[w * 16 * LDP];
        #pragma unroll
        for (int r = 0; r < 4; ++r) {
            float p0 = exp2f((s0[r] - m_r[r]) * L2E) * linv[r];
            float p1 = exp2f((s1[r] - m_r[r]) * L2E) * linv[r];
            Pw[(quad * 4 + r) * LDP + lane15]      = (_Float16)p0;
            Pw[(quad * 4 + r) * LDP + 16 + lane15] = (_Float16)p1;
        }
        __syncthreads();

        half8 ap = *(const half8*)(&Pw[lane15 * LDP + quad * 8]);
        const _Float16* vbase = &Vt[(size_t)lane15 * LDV + quad * 8];
        #pragma unroll
        for (int nt = 0; nt < 32; ++nt) {
            const _Float16* vp = vbase + nt * 16 * LDV;
            half4v blo = *(const half4v*)(vp);
            half4v bhi = *(const half4v*)(vp + 4);
            half8 bv;
            bv[0] = blo[0]; bv[1] = blo[1]; bv[2] = blo[2]; bv[3] = blo[3];
            bv[4] = bhi[0]; bv[5] = bhi[1]; bv[6] = bhi[2]; bv[7] = bhi[3];
            accO[nt] = __builtin_amdgcn_mfma_f32_16x16x32_f16(ap, bv, accO[nt], 0, 0, 0);
        }
    }

    // ---- write out: O rows = quad*4+r, cols = nt*16+lane15 ----
    float* yb = y + ((size_t)b * BN * BD) + (size_t)(q0 + w * 16) * BD;
    #pragma unroll
    for (int nt = 0; nt < 32; ++nt) {
        #pragma unroll
        for (int r = 0; r < 4; ++r) {
            yb[(quad * 4 + r) * BD + nt * 16 + lane15] = accO[nt][r];
        }
    }
}

extern "C" void kernel_launch(void* const* d_in, const int* in_sizes, int n_in,
                              void* d_out, int out_size, void* d_ws, size_t ws_size,
                              hipStream_t stream) {
    const float* x = (const float*)d_in[0];
    float* yo = (float*)d_out;
    dim3 grid(BN / 64, 8, 1);   // 32 q-blocks x 8 batches = 256 WGs
    dim3 block(256, 1, 1);
    attn_kernel<<<grid, block, 0, stream>>>(x, yo);
}

// Round 2
// 259.528 us; speedup vs baseline: 1.9932x; 1.9932x over previous
//
#include <hip/hip_runtime.h>

typedef _Float16 half8  __attribute__((ext_vector_type(8)));
typedef _Float16 half4v __attribute__((ext_vector_type(4)));
typedef _Float16 half2v __attribute__((ext_vector_type(2)));
typedef float  float4v  __attribute__((ext_vector_type(4)));

#define BN 2048
#define BD 512
#define NK 32        // keys per tile
#define LDK 520      // K_lds pitch (fp16): 1040 B rows, 16B-aligned
#define LDV 40       // Vt pitch (fp16): 80 B rows, 16B-aligned, chunk-swizzled
#define LDP 40       // P pitch (fp16): 80 B rows, 16B-aligned
#define L2E 1.44269504f

__global__ __launch_bounds__(256, 1)
void attn_kernel(const float* __restrict__ x, float* __restrict__ y)
{
    __shared__ __align__(16) _Float16 Kl[NK * LDK];      // 33,280 B [key][dim]
    __shared__ __align__(16) _Float16 Vt[BD * LDV];      // 40,960 B [dim][key], swizzled
    __shared__ __align__(16) _Float16 Pl[4 * 16 * LDP];  //  5,120 B per-wave P
    __shared__ float Qn[64];                             // per-row ||q||^2 (softmax shift)

    const int t      = threadIdx.x;
    const int w      = t >> 6;
    const int lane   = t & 63;
    const int lane15 = lane & 15;
    const int quad   = lane >> 4;

    const int b  = blockIdx.y;
    const int q0 = blockIdx.x * 64;
    const float* xb = x + ((size_t)b * BN * BD);

    // ---- Q preload (A-frags) + fp32 row norm^2 for the softmax shift ----
    half8 qf[16];
    {
        float qn = 0.0f;
        const float* qrow = xb + (size_t)(q0 + w * 16 + lane15) * BD + quad * 8;
        #pragma unroll
        for (int ks = 0; ks < 16; ++ks) {
            float4v a = *(const float4v*)(qrow + ks * 32);
            float4v c = *(const float4v*)(qrow + ks * 32 + 4);
            half8 q;
            q[0] = (_Float16)a[0]; q[1] = (_Float16)a[1];
            q[2] = (_Float16)a[2]; q[3] = (_Float16)a[3];
            q[4] = (_Float16)c[0]; q[5] = (_Float16)c[1];
            q[6] = (_Float16)c[2]; q[7] = (_Float16)c[3];
            qf[ks] = q;
            qn += a[0]*a[0] + a[1]*a[1] + a[2]*a[2] + a[3]*a[3]
                + c[0]*c[0] + c[1]*c[1] + c[2]*c[2] + c[3]*c[3];
        }
        qn += __shfl_xor(qn, 16);
        qn += __shfl_xor(qn, 32);
        if (lane < 16) Qn[w * 16 + lane15] = qn;
    }
    __syncthreads();
    float m4[4];
    #pragma unroll
    for (int r = 0; r < 4; ++r) m4[r] = Qn[w * 16 + quad * 4 + r];

    // ---- staging mapping + register prefetch ----
    const int d4 = t & 15;     // dim-quad lane (coalesced global)
    const int kp = t >> 4;     // key-pair 0..15
    const int vswz = d4 & 3;   // Vt chunk swizzle for this thread's dims

    float4v ga[8], gb[8];
    auto load_tile = [&](int kt) {
        const float* r0 = xb + (size_t)(kt * NK + 2 * kp) * BD;
        #pragma unroll
        for (int it = 0; it < 8; ++it) {
            const int d = (d4 + (it << 4)) << 2;
            ga[it] = *(const float4v*)(r0 + d);
            gb[it] = *(const float4v*)(r0 + BD + d);
        }
    };
    auto store_tile = [&]() {
        #pragma unroll
        for (int it = 0; it < 8; ++it) {
            const int d = (d4 + (it << 4)) << 2;
            half4v ha, hb;
            ha[0] = (_Float16)ga[it][0]; ha[1] = (_Float16)ga[it][1];
            ha[2] = (_Float16)ga[it][2]; ha[3] = (_Float16)ga[it][3];
            hb[0] = (_Float16)gb[it][0]; hb[1] = (_Float16)gb[it][1];
            hb[2] = (_Float16)gb[it][2]; hb[3] = (_Float16)gb[it][3];
            *(half4v*)(&Kl[(2 * kp)     * LDK + d]) = ha;
            *(half4v*)(&Kl[(2 * kp + 1) * LDK + d]) = hb;
            const int col = 2 * ((kp + 4 * vswz) & 15);   // swizzled key-pair column
            #pragma unroll
            for (int i = 0; i < 4; ++i) {
                half2v p; p[0] = ha[i]; p[1] = hb[i];
                *(half2v*)(&Vt[(d + i) * LDV + col]) = p;
            }
        }
    };

    float4v accO[32];
    #pragma unroll
    for (int nt = 0; nt < 32; ++nt) accO[nt] = (float4v){0.f, 0.f, 0.f, 0.f};
    float l_r[4] = {0.f, 0.f, 0.f, 0.f};

    load_tile(0);

    // ---- single pass: QK^T -> exp(s - ||q||^2) -> O += P*V ----
    for (int kt = 0; kt < BN / NK; ++kt) {
        __syncthreads();          // all waves done reading previous tile
        store_tile();             // cvt + LDS write from prefetch regs
        __syncthreads();
        if (kt + 1 < BN / NK) load_tile(kt + 1);   // hide under QK+PV below

        float4v s0 = {0.f, 0.f, 0.f, 0.f}, s1 = {0.f, 0.f, 0.f, 0.f};
        {
            const _Float16* kr0 = &Kl[lane15 * LDK + quad * 8];
            const _Float16* kr1 = kr0 + 16 * LDK;
            #pragma unroll
            for (int ks = 0; ks < 16; ++ks) {
                half8 b0 = *(const half8*)(kr0 + ks * 32);
                half8 b1 = *(const half8*)(kr1 + ks * 32);
                s0 = __builtin_amdgcn_mfma_f32_16x16x32_f16(qf[ks], b0, s0, 0, 0, 0);
                s1 = __builtin_amdgcn_mfma_f32_16x16x32_f16(qf[ks], b1, s1, 0, 0, 0);
            }
        }

        // unnormalized P; denominator deferred (plain sum, no rescale ever)
        _Float16* Pw = &Pl[w * 16 * LDP];
        #pragma unroll
        for (int r = 0; r < 4; ++r) {
            float p0 = exp2f((s0[r] - m4[r]) * L2E);
            float p1 = exp2f((s1[r] - m4[r]) * L2E);
            l_r[r] += p0 + p1;
            Pw[(quad * 4 + r) * LDP + lane15]      = (_Float16)p0;
            Pw[(quad * 4 + r) * LDP + 16 + lane15] = (_Float16)p1;
        }
        // per-wave buffer: intra-wave lgkmcnt ordering suffices, no barrier

        half8 ap = *(const half8*)(&Pw[lane15 * LDP + quad * 8]);
        const _Float16* vbase = &Vt[(size_t)lane15 * LDV + 8 * ((quad + (lane15 >> 2)) & 3)];
        #pragma unroll
        for (int nt = 0; nt < 32; ++nt) {
            half8 bv = *(const half8*)(vbase + nt * 16 * LDV);
            accO[nt] = __builtin_amdgcn_mfma_f32_16x16x32_f16(ap, bv, accO[nt], 0, 0, 0);
        }
    }

    // ---- denominator: reduce per-lane partials across the 16 col-lanes ----
    float linv[4];
    #pragma unroll
    for (int r = 0; r < 4; ++r) {
        float l = l_r[r];
        l += __shfl_xor(l, 1);
        l += __shfl_xor(l, 2);
        l += __shfl_xor(l, 4);
        l += __shfl_xor(l, 8);
        linv[r] = 1.0f / l;
    }

    // ---- epilogue: O rows = quad*4+r, cols = nt*16+lane15, scale by 1/l ----
    float* yb = y + ((size_t)b * BN * BD) + (size_t)(q0 + w * 16) * BD;
    #pragma unroll
    for (int nt = 0; nt < 32; ++nt) {
        #pragma unroll
        for (int r = 0; r < 4; ++r) {
            yb[(quad * 4 + r) * BD + nt * 16 + lane15] = accO[nt][r] * linv[r];
        }
    }
}

extern "C" void kernel_launch(void* const* d_in, const int* in_sizes, int n_in,
                              void* d_out, int out_size, void* d_ws, size_t ws_size,
                              hipStream_t stream) {
    const float* x = (const float*)d_in[0];
    float* yo = (float*)d_out;
    dim3 grid(BN / 64, 8, 1);   // 32 q-blocks x 8 batches = 256 WGs (1/CU)
    dim3 block(256, 1, 1);
    attn_kernel<<<grid, block, 0, stream>>>(x, yo);
}